// Round 1
// baseline (74.807 us; speedup 1.0000x reference)
//
#include <hip/hip_runtime.h>

#define HH 1024
#define WW 1024
#define EPSF 1e-10f

// Each thread: one row h, 4 consecutive columns w0..w0+3.
// Batch outputs are identical (inputs broadcast from batch 1) -> compute once, store 4x.
__global__ __launch_bounds__(256) void spline_kernel(
    const float* __restrict__ tp,   // [16,2] train points (normalized)
    const float* __restrict__ ww,   // [16,1] rbf weights
    const float* __restrict__ vw,   // [3,1]  linear weights
    float* __restrict__ out)        // [4, HH, WW]
{
    const int t  = blockIdx.x * blockDim.x + threadIdx.x;  // [0, HH*WW/4)
    const int h  = t >> 8;                                 // WW/4 = 256 quads per row
    const int w0 = (t & 255) << 2;

    const float inv = 1.0f / ((float)WW * (float)WW * (float)HH * (float)HH);
    const float hf  = (float)h;

    float tx[16], wm[16], dy2[16];
#pragma unroll
    for (int m = 0; m < 16; ++m) {
        tx[m]    = tp[2 * m] * (float)WW;
        float ty = tp[2 * m + 1] * (float)HH;
        wm[m]    = ww[m] * inv;
        float dy = hf - ty;
        dy2[m]   = dy * dy;
    }
    const float v0 = vw[0], v1 = vw[1], v2 = vw[2];
    const float base = fmaf(hf, v1, v2);   // h*v1 + v2, shared across the quad

    float4 res;
    float* r = reinterpret_cast<float*>(&res);
#pragma unroll
    for (int j = 0; j < 4; ++j) {
        const float wf = (float)(w0 + j);
        float acc = fmaf(wf, v0, base);    // linear term
#pragma unroll
        for (int m = 0; m < 16; ++m) {
            float dx  = wf - tx[m];
            float r2  = fmaf(dx, dx, dy2[m]);
            r2        = fmaxf(r2, EPSF);
            float phi = r2 * __builtin_amdgcn_sqrtf(r2);   // r2^1.5 (ORDER=3)
            acc       = fmaf(phi, wm[m], acc);
        }
        r[j] = acc;
    }

    const int off = h * WW + w0;
#pragma unroll
    for (int b = 0; b < 4; ++b) {
        *reinterpret_cast<float4*>(out + b * (HH * WW) + off) = res;
    }
}

extern "C" void kernel_launch(void* const* d_in, const int* in_sizes, int n_in,
                              void* d_out, int out_size, void* d_ws, size_t ws_size,
                              hipStream_t stream) {
    // d_in[0] = x (unused, shape only), d_in[1] = train_points, d_in[2] = ww, d_in[3] = vw
    const float* tp = (const float*)d_in[1];
    const float* ww = (const float*)d_in[2];
    const float* vw = (const float*)d_in[3];
    float* out = (float*)d_out;

    dim3 grid((HH * WW / 4) / 256);
    dim3 block(256);
    spline_kernel<<<grid, block, 0, stream>>>(tp, ww, vw, out);
}

// Round 3
// 74.499 us; speedup vs baseline: 1.0041x; 1.0041x over previous
//
#include <hip/hip_runtime.h>

#define HH 1024
#define WW 1024
#define EPSF 1e-10f

typedef float floatx4 __attribute__((ext_vector_type(4)));  // native vector: OK for nontemporal builtin

// Each thread: one row h, 8 consecutive columns w0..w0+7.
// Batch outputs are identical (inputs broadcast from batch 1) -> compute once, store 4x.
__global__ __launch_bounds__(256) void spline_kernel(
    const float* __restrict__ tp,   // [16,2] train points (normalized)
    const float* __restrict__ ww,   // [16,1] rbf weights
    const float* __restrict__ vw,   // [3,1]  linear weights
    float* __restrict__ out)        // [4, HH, WW]
{
    const int t  = blockIdx.x * blockDim.x + threadIdx.x;  // [0, HH*WW/8)
    const int h  = t >> 7;                                 // 128 octets per row
    const int w0 = (t & 127) << 3;

    const float inv = 1.0f / ((float)WW * (float)WW * (float)HH * (float)HH);
    const float hf  = (float)h;

    float tx[16], wm[16], dy2[16];
#pragma unroll
    for (int m = 0; m < 16; ++m) {
        tx[m]    = tp[2 * m] * (float)WW;      // uniform -> s_load + scalar math
        float ty = tp[2 * m + 1] * (float)HH;
        wm[m]    = ww[m] * inv;
        float dy = hf - ty;
        dy2[m]   = dy * dy;
    }
    const float v0 = vw[0], v1 = vw[1], v2 = vw[2];
    const float base = fmaf(hf, v1, v2);   // h*v1 + v2, shared across the 8 columns

    float res[8];
#pragma unroll
    for (int j = 0; j < 8; ++j) {
        const float wf = (float)(w0 + j);
        float acc = fmaf(wf, v0, base);    // linear term
#pragma unroll
        for (int m = 0; m < 16; ++m) {
            float dx  = wf - tx[m];
            float r2  = fmaf(dx, dx, dy2[m]);
            r2        = fmaxf(r2, EPSF);
            float phi = r2 * __builtin_amdgcn_sqrtf(r2);   // r2^1.5 (ORDER=3)
            acc       = fmaf(phi, wm[m], acc);
        }
        res[j] = acc;
    }

    floatx4 lo = { res[0], res[1], res[2], res[3] };
    floatx4 hi = { res[4], res[5], res[6], res[7] };
    const int off = h * WW + w0;
#pragma unroll
    for (int b = 0; b < 4; ++b) {
        floatx4* p = reinterpret_cast<floatx4*>(out + b * (HH * WW) + off);
        __builtin_nontemporal_store(lo, p);      // write-once data: stream past L2
        __builtin_nontemporal_store(hi, p + 1);
    }
}

extern "C" void kernel_launch(void* const* d_in, const int* in_sizes, int n_in,
                              void* d_out, int out_size, void* d_ws, size_t ws_size,
                              hipStream_t stream) {
    // d_in[0] = x (unused, shape only), d_in[1] = train_points, d_in[2] = ww, d_in[3] = vw
    const float* tp = (const float*)d_in[1];
    const float* ww = (const float*)d_in[2];
    const float* vw = (const float*)d_in[3];
    float* out = (float*)d_out;

    dim3 grid((HH * WW / 8) / 256);   // 512 blocks
    dim3 block(256);
    spline_kernel<<<grid, block, 0, stream>>>(tp, ww, vw, out);
}